// Round 14
// baseline (138.546 us; speedup 1.0000x reference)
//
#include <hip/hip_runtime.h>
#include <hip/hip_bf16.h>
#include <math.h>

#define DIM 384
#define NH 6
#define DH 64
#define B_ 2
#define S_ 2048
#define EPS 1e-6f
#define LN_EPS 1e-5f
#define G3 (3*DIM)   // 1152
#define LOG2E 1.44269504f
#define KSTR 72      // LDS row stride (ushort): 144 B -> 4-bank rotate/row
#define NT (S_/64)   // 32 64-tiles per (b,h)
#define NT2 (S_/128) // 16 macro (128-row) q-tiles per (b,h)
#define NSPLIT 4     // t-range splits per macro q-tile
#define NBH (B_*NH)  // 12
#define NGATE (B_*S_/4)  // 1024 gate blocks

typedef __attribute__((ext_vector_type(8))) short bf16x8;
typedef __attribute__((ext_vector_type(4))) short bf16x4;
typedef __attribute__((ext_vector_type(4))) float f32x4;
typedef __attribute__((ext_vector_type(8))) unsigned short u16x8;

__device__ __forceinline__ unsigned short f2bf(float f){
    unsigned int u = __float_as_uint(f);
    u += 0x7fff + ((u >> 16) & 1);   // round-to-nearest-even
    return (unsigned short)(u >> 16);
}
__device__ __forceinline__ float bf2f(unsigned short u){
    return __uint_as_float(((unsigned int)u) << 16);
}
__device__ __forceinline__ float logsig(float x){
    return fminf(x, 0.f) - log1pf(expf(-fabsf(x)));
}
// packed f32x4 -> bf16x4 via v_cvt_pk_bf16_f32 (round-13: manual f2bf was
// ~4 VALU instr/value; packed cvt is 1 instr per pair)
__device__ __forceinline__ bf16x4 pack4(float a, float b, float c, float d){
    union { __hip_bfloat162 h2[2]; bf16x4 v; } u;
    u.h2[0] = __float22bfloat162_rn(make_float2(a, b));
    u.h2[1] = __float22bfloat162_rn(make_float2(c, d));
    return u.v;
}

// ---------------- Kernel 1: gates + Q/K bf16 emission + V-transpose ----------
__global__ __launch_bounds__(256) void gates_kernel(
    const float* __restrict__ q, const float* __restrict__ k, const float* __restrict__ v,
    const float* __restrict__ iw, const float* __restrict__ ib,
    const float* __restrict__ fw, const float* __restrict__ fb,
    float* __restrict__ ig_out, float* __restrict__ lf_out,
    unsigned short* __restrict__ Qb, unsigned short* __restrict__ Kb,
    unsigned short* __restrict__ Vt) {
    __shared__ unsigned short lt[64*KSTR];
    int tid = threadIdx.x;
    if (blockIdx.x >= NGATE){
        // ---- V -> bf16 pre-transposed Vt[bh][d][t] ----
        int lin = blockIdx.x - NGATE;     // 0..NBH*NT-1
        int bh = lin / NT;
        int t0 = (lin % NT) * 64;
        int b = bh / NH, h = bh % NH;
        #pragma unroll
        for (int i = 0; i < 4; i++){
            int idx = tid + 256*i;
            int r = idx >> 4;
            int c4 = (idx & 15) * 4;
            float4 x = *(const float4*)(v + ((size_t)b*S_ + t0 + r)*DIM + h*DH + c4);
            lt[(c4+0)*KSTR + r] = f2bf(x.x);
            lt[(c4+1)*KSTR + r] = f2bf(x.y);
            lt[(c4+2)*KSTR + r] = f2bf(x.z);
            lt[(c4+3)*KSTR + r] = f2bf(x.w);
        }
        __syncthreads();
        #pragma unroll
        for (int i = 0; i < 2; i++){
            int idx = tid + 256*i;
            int d = idx >> 3;
            int t8 = (idx & 7) * 8;
            u16x8 o = *(const u16x8*)&lt[d*KSTR + t8];
            *(u16x8*)(Vt + (size_t)bh*DH*S_ + (size_t)d*S_ + t0 + t8) = o;
        }
        return;
    }
    int wave = (blockIdx.x * 256 + tid) >> 6;
    int lane = tid & 63;
    int b = wave / S_, s = wave % S_;
    size_t base = ((size_t)b * S_ + s) * DIM;
    float aI[NH], aF[NH];
    #pragma unroll
    for (int h = 0; h < NH; h++){ aI[h] = 0.f; aF[h] = 0.f; }
    for (int g = lane; g < G3/4; g += 64) {
        int e = g * 4;
        float4 x4;
        if (e < DIM){
            x4 = *(const float4*)(q + base + e);
            ushort4 t; t.x=f2bf(x4.x*0.125f); t.y=f2bf(x4.y*0.125f);
            t.z=f2bf(x4.z*0.125f); t.w=f2bf(x4.w*0.125f);
            *(ushort4*)(Qb + base + e) = t;
        } else if (e < 2*DIM){
            x4 = *(const float4*)(k + base + e - DIM);
            ushort4 t; t.x=f2bf(x4.x); t.y=f2bf(x4.y); t.z=f2bf(x4.z); t.w=f2bf(x4.w);
            *(ushort4*)(Kb + base + e - DIM) = t;
        } else {
            x4 = *(const float4*)(v + base + e - 2*DIM);
        }
        #pragma unroll
        for (int h = 0; h < NH; h++){
            float4 wi = *(const float4*)(iw + h*G3 + e);
            float4 wf = *(const float4*)(fw + h*G3 + e);
            aI[h] = fmaf(x4.x, wi.x, fmaf(x4.y, wi.y, fmaf(x4.z, wi.z, fmaf(x4.w, wi.w, aI[h]))));
            aF[h] = fmaf(x4.x, wf.x, fmaf(x4.y, wf.y, fmaf(x4.z, wf.z, fmaf(x4.w, wf.w, aF[h]))));
        }
    }
    #pragma unroll
    for (int h = 0; h < NH; h++){
        #pragma unroll
        for (int off = 32; off >= 1; off >>= 1){
            aI[h] += __shfl_xor(aI[h], off, 64);
            aF[h] += __shfl_xor(aF[h], off, 64);
        }
    }
    if (lane == 0) {
        #pragma unroll
        for (int h = 0; h < NH; h++){
            ig_out[((size_t)b*NH + h)*S_ + s] = aI[h] + ib[h];
            lf_out[((size_t)b*NH + h)*S_ + s] = logsig(aF[h] + fb[h]);
        }
    }
}

// ---------------- Kernel 2: scan + decay-factor precompute -------------------
__global__ __launch_bounds__(256) void scan_kernel(
    const float* __restrict__ lf, const float* __restrict__ ig,
    float* __restrict__ cum, float* __restrict__ e2, float* __restrict__ pm,
    float* __restrict__ gA, float* __restrict__ baseA){
    int bh = blockIdx.x;
    const float* srcL = lf + (size_t)bh * S_;
    const float* srcI = ig + (size_t)bh * S_;
    float* dstC = cum + (size_t)bh * S_;
    float* dstE = e2 + (size_t)bh * S_;
    float* dstP = pm + (size_t)bh * S_;
    int tid = threadIdx.x;
    float loc[8];
    float run = 0.f;
    #pragma unroll
    for (int j = 0; j < 8; j++){ run += srcL[tid*8 + j]; loc[j] = run; }
    __shared__ float sm[256];
    sm[tid] = run;
    __syncthreads();
    float total = run;
    for (int off = 1; off < 256; off <<= 1){
        float vv = (tid >= off) ? sm[tid - off] : 0.f;
        __syncthreads();
        sm[tid] += vv;
        __syncthreads();
    }
    float excl = sm[tid] - total;
    float c[8];
    #pragma unroll
    for (int j = 0; j < 8; j++){ c[j] = excl + loc[j]; dstC[tid*8 + j] = c[j]; }
    __shared__ float sb[32];
    if ((tid & 7) == 0) sb[tid >> 3] = excl;
    __syncthreads();
    float base_t = sb[tid >> 3];
    float E[8], mloc = -INFINITY;
    #pragma unroll
    for (int j = 0; j < 8; j++){
        E[j] = srcI[tid*8 + j] - c[j] + base_t;
        dstE[tid*8 + j] = exp2f(E[j] * LOG2E);
        mloc = fmaxf(mloc, E[j]);
    }
    __shared__ float smax[256];
    smax[tid] = mloc;
    __syncthreads();
    float carry = -INFINITY;
    int g0 = tid & ~7;
    for (int u = g0; u < tid; u++) carry = fmaxf(carry, smax[u]);
    float runm = carry;
    #pragma unroll
    for (int j = 0; j < 8; j++){
        runm = fmaxf(runm, E[j]);
        dstP[tid*8 + j] = runm;
    }
    if ((tid & 7) == 7) gA[bh*NT + (tid >> 3)] = runm - base_t;
    if ((tid & 7) == 0) baseA[bh*NT + (tid >> 3)] = base_t;
}

// ---------------- Kernel 3a: split-T partial flash-mLSTM (2 q-stripes/wave) --
// Round-14: 128-row macro q-tile; each staged K/V tile feeds TWO 16-row
// q-stripes per wave -> staging/barrier/loop overhead per unit work halves.
// Stripe 0 diag tile = 2qt, stripe 1 diag = 2qt+1; stripe 0 skips tile 2qt+1
// (block-uniform). Fixed-max softmax (R13) per stripe; packed bf16 cvt.
__global__ __launch_bounds__(256) void mlstm_part(
    const unsigned short* __restrict__ Qb, const unsigned short* __restrict__ Kb,
    const unsigned short* __restrict__ Vt,
    const float* __restrict__ cum, const float* __restrict__ e2,
    const float* __restrict__ pm, const float* __restrict__ gA,
    const float* __restrict__ baseA,
    unsigned short* __restrict__ pOb, float* __restrict__ pM, float* __restrict__ pL) {
    int lin = blockIdx.x;            // 0..NBH*NT2*NSPLIT-1 (768)
    int sp  = lin / NBH;             // split-slot, longest q-tiles first
    int bh  = lin % NBH;
    int qt  = (NT2 - 1) - (sp >> 2);
    int c   = sp & 3;
    int ntile = 2*qt + 2;            // t-tiles in causal span of 128 q-rows
    int L   = (ntile + 3) >> 2;
    int tb0 = c * L;
    int tb1 = min((c + 1) * L, ntile);
    int pblk = lin;
    int tid = threadIdx.x;

    if (tb0 >= tb1){                 // empty split: neutral partial, exit
        if (tid < 128){ pM[pblk*128 + tid] = -INFINITY; pL[pblk*128 + tid] = 0.f; }
        return;
    }

    __shared__ unsigned short kt[2][64*KSTR];   // kt[buf][t][d]
    __shared__ unsigned short vt[2][64*KSTR];   // vt[buf][d][t]

    int b = bh / NH, h = bh % NH;
    int s0 = qt * 128;
    int wv   = tid >> 6;
    int lane = tid & 63;
    int lq   = lane & 15;
    int quad = lane >> 4;

    const unsigned short* kbT = Kb + (size_t)b*S_*DIM + h*DH;
    const unsigned short* vtB = Vt + (size_t)bh*DH*S_;
    const float* cmb = cum + (size_t)bh*S_;
    const float* e2b = e2 + (size_t)bh*S_;
    const float* gB = gA + bh*NT;
    const float* baseB = baseA + bh*NT;

    int s_glob[2];
    bf16x8 qf[2][2];
    float cq[2], m[2], mn[2], b_loc[2];
    f32x4 oacc[2][4];
    #pragma unroll
    for (int ss = 0; ss < 2; ss++){
        s_glob[ss] = s0 + 64*ss + 16*wv + lq;
        const unsigned short* qr = Qb + ((size_t)b*S_ + s_glob[ss])*DIM + h*DH;
        qf[ss][0] = *(const bf16x8*)(qr + 8*quad);
        qf[ss][1] = *(const bf16x8*)(qr + 32 + 8*quad);
        cq[ss] = cmb[s_glob[ss]];
        float pm_s = pm[(size_t)bh*S_ + s_glob[ss]];
        int dg = 2*qt + ss;
        float mm = -INFINITY;
        int hi = min(tb1, dg + 1);
        for (int tix = tb0; tix < hi; tix++)
            mm = fmaxf(mm, (tix == dg) ? (pm_s - baseB[tix]) : gB[tix]);
        m[ss] = mm;
        mn[ss] = cq[ss] + mm;        // -inf if stripe range empty
        b_loc[ss] = 0.f;
        #pragma unroll
        for (int cg = 0; cg < 4; cg++) oacc[ss][cg] = (f32x4){0.f,0.f,0.f,0.f};
    }

    int sr[2], sc[2];
    #pragma unroll
    for (int i = 0; i < 2; i++){
        int idx = tid + 256*i;
        sr[i] = idx >> 3;
        sc[i] = (idx & 7) * 8;
    }

    // preload + stage tile tb0 into buffer 0
    u16x8 kreg[2], vreg[2];
    {
        const unsigned short* kb = kbT + (size_t)(tb0*64)*DIM;
        const unsigned short* vb = vtB + tb0*64;
        #pragma unroll
        for (int i = 0; i < 2; i++){
            kreg[i] = *(const u16x8*)(kb + (size_t)sr[i]*DIM + sc[i]);
            vreg[i] = *(const u16x8*)(vb + (size_t)sr[i]*S_ + sc[i]);
        }
        #pragma unroll
        for (int i = 0; i < 2; i++){
            *(u16x8*)&kt[0][sr[i]*KSTR + sc[i]] = kreg[i];
            *(u16x8*)&vt[0][sr[i]*KSTR + sc[i]] = vreg[i];
        }
    }
    __syncthreads();

    int bufi = 0;
    for (int t0 = tb0*64; t0 < tb1*64; t0 += 64){
        bool more = (t0 + 64 < tb1*64);
        if (more){
            const unsigned short* kb = kbT + (size_t)(t0 + 64)*DIM;
            const unsigned short* vb = vtB + (t0 + 64);
            #pragma unroll
            for (int i = 0; i < 2; i++){
                kreg[i] = *(const u16x8*)(kb + (size_t)sr[i]*DIM + sc[i]);
                vreg[i] = *(const u16x8*)(vb + (size_t)sr[i]*S_ + sc[i]);
            }
        }

        int tix = t0 >> 6;
        float base_t = baseB[tix];
        float4 e2v[4];
        #pragma unroll
        for (int tb = 0; tb < 4; tb++)
            e2v[tb] = *(const float4*)(e2b + t0 + 16*tb + 4*quad);

        const unsigned short* ktc = kt[bufi];
        const unsigned short* vtc = vt[bufi];

        #pragma unroll
        for (int ss = 0; ss < 2; ss++){
            int dg = 2*qt + ss;
            if (tix > dg) continue;          // only stripe 0 at tix==2qt+1
            float ws = exp2f(-(m[ss] + base_t) * LOG2E);

            // ---- matmul1: S^T blocks ----
            f32x4 st4[4];
            #pragma unroll
            for (int tb = 0; tb < 4; tb++) st4[tb] = (f32x4){0.f,0.f,0.f,0.f};
            #pragma unroll
            for (int ks = 0; ks < 2; ks++){
                #pragma unroll
                for (int tb = 0; tb < 4; tb++){
                    bf16x8 af = *(const bf16x8*)&ktc[(16*tb + lq)*KSTR + 32*ks + 8*quad];
                    st4[tb] = __builtin_amdgcn_mfma_f32_16x16x32_bf16(af, qf[ss][ks], st4[tb], 0, 0, 0);
                }
            }

            // ---- fixed-max softmax ----
            bool diag = (tix == dg);
            float pv[4][4];
            #pragma unroll
            for (int tb = 0; tb < 4; tb++)
                #pragma unroll
                for (int r = 0; r < 4; r++)
                    pv[tb][r] = st4[tb][r] * (ws * e2v[tb][r]);
            if (diag){
                #pragma unroll
                for (int tb = 0; tb < 4; tb++)
                    #pragma unroll
                    for (int r = 0; r < 4; r++)
                        if (t0 + 16*tb + 4*quad + r > s_glob[ss]) pv[tb][r] = 0.f;
            }
            bf16x4 pf[4];
            #pragma unroll
            for (int tb = 0; tb < 4; tb++){
                b_loc[ss] += (pv[tb][0] + pv[tb][1]) + (pv[tb][2] + pv[tb][3]);
                pf[tb] = pack4(pv[tb][0], pv[tb][1], pv[tb][2], pv[tb][3]);
            }

            // ---- matmul2: O += P @ V ----
            #pragma unroll
            for (int tb = 0; tb < 4; tb++){
                #pragma unroll
                for (int cg = 0; cg < 4; cg++){
                    bf16x4 vf = *(const bf16x4*)&vtc[(16*cg + lq)*KSTR + 16*tb + 4*quad];
                    oacc[ss][cg] = __builtin_amdgcn_mfma_f32_16x16x16bf16_1k(pf[tb], vf, oacc[ss][cg], 0, 0, 0);
                }
            }
        }

        if (more){
            #pragma unroll
            for (int i = 0; i < 2; i++){
                *(u16x8*)&kt[bufi^1][sr[i]*KSTR + sc[i]] = kreg[i];
                *(u16x8*)&vt[bufi^1][sr[i]*KSTR + sc[i]] = vreg[i];
            }
            __syncthreads();
            bufi ^= 1;
        }
    }

    // ---- deferred row-sum reduction + write partials (bf16) ----
    unsigned short* po = pOb + (size_t)pblk * 8192;
    #pragma unroll
    for (int ss = 0; ss < 2; ss++){
        b_loc[ss] += __shfl_xor(b_loc[ss], 16, 64);
        b_loc[ss] += __shfl_xor(b_loc[ss], 32, 64);
        #pragma unroll
        for (int r = 0; r < 4; r++){
            int row = 64*ss + 16*wv + 4*quad + r;
            #pragma unroll
            for (int cg = 0; cg < 4; cg++)
                po[row*64 + 16*cg + lq] = f2bf(oacc[ss][cg][r]);
        }
        if (quad == 0){
            pM[pblk*128 + 64*ss + 16*wv + lq] = mn[ss];
            pL[pblk*128 + 64*ss + 16*wv + lq] = b_loc[ss];
        }
    }
}

// ---------------- Kernel 3b: combine partials + normalizer + LayerNorm -------
__global__ __launch_bounds__(256) void mlstm_combine(
    const unsigned short* __restrict__ pOb, const float* __restrict__ pM,
    const float* __restrict__ pL, const float* __restrict__ w,
    float* __restrict__ out) {
    int qt = blockIdx.x;           // 0..NT2-1
    int bh = blockIdx.y;
    int b = bh / NH, h = bh % NH;
    int tid = threadIdx.x;
    int cl = (tid & 15) * 4;       // col base (x4)
    int rb = tid >> 4;             // row within 16-row band

    int pblk[NSPLIT];
    #pragma unroll
    for (int p = 0; p < NSPLIT; p++)
        pblk[p] = (((NT2 - 1 - qt) << 2) + p) * NBH + bh;

    float4 wv4 = *(const float4*)(w + h*DH + cl);

    #pragma unroll
    for (int pass = 0; pass < 8; pass++){
        int row = pass*16 + rb;
        float mp[NSPLIT], lp[NSPLIT];
        float mmax = -INFINITY;
        #pragma unroll
        for (int p = 0; p < NSPLIT; p++){
            mp[p] = pM[pblk[p]*128 + row];
            lp[p] = pL[pblk[p]*128 + row];
            mmax = fmaxf(mmax, mp[p]);
        }
        float l = 0.f;
        float ox = 0.f, oy = 0.f, oz = 0.f, ow = 0.f;
        #pragma unroll
        for (int p = 0; p < NSPLIT; p++){
            if (mp[p] != -INFINITY){           // skip empty splits/stripes
                float wp = exp2f((mp[p] - mmax) * LOG2E);
                l += wp * lp[p];
                ushort4 t4 = *(const ushort4*)(pOb + (size_t)pblk[p]*8192 + row*64 + cl);
                ox += wp*bf2f(t4.x); oy += wp*bf2f(t4.y);
                oz += wp*bf2f(t4.z); ow += wp*bf2f(t4.w);
            }
        }
        float nrm = fmaxf(fabsf(l), exp2f(-mmax * LOG2E));
        float inv = 1.f / (nrm + EPS);
        float x[4] = {ox*inv, oy*inv, oz*inv, ow*inv};
        float s1 = x[0]+x[1]+x[2]+x[3];
        float s2 = x[0]*x[0]+x[1]*x[1]+x[2]*x[2]+x[3]*x[3];
        #pragma unroll
        for (int off = 8; off >= 1; off >>= 1){
            s1 += __shfl_xor(s1, off, 64);
            s2 += __shfl_xor(s2, off, 64);
        }
        float mean = s1 * (1.f/64.f);
        float var  = s2 * (1.f/64.f) - mean*mean;
        float rstd = rsqrtf(var + LN_EPS);
        float4 oo;
        oo.x = (x[0]-mean)*rstd*(1.f + wv4.x);
        oo.y = (x[1]-mean)*rstd*(1.f + wv4.y);
        oo.z = (x[2]-mean)*rstd*(1.f + wv4.z);
        oo.w = (x[3]-mean)*rstd*(1.f + wv4.w);
        *(float4*)(out + ((size_t)b*S_ + qt*128 + row)*DIM + h*DH + cl) = oo;
    }
}

extern "C" void kernel_launch(void* const* d_in, const int* in_sizes, int n_in,
                              void* d_out, int out_size, void* d_ws, size_t ws_size,
                              hipStream_t stream) {
    const float* q  = (const float*)d_in[0];
    const float* k  = (const float*)d_in[1];
    const float* v  = (const float*)d_in[2];
    const float* iw = (const float*)d_in[3];
    const float* ib = (const float*)d_in[4];
    const float* fw = (const float*)d_in[5];
    const float* fb = (const float*)d_in[6];
    const float* w  = (const float*)d_in[7];
    float* out = (float*)d_out;

    const int nPart = NBH * NT2 * NSPLIT;      // 768
    const size_t NE = (size_t)B_ * S_ * DIM;   // 1.57M elems
    float* ig   = (float*)d_ws;                // NBH*S
    float* lf   = ig   + (size_t)NBH*S_;
    float* cum  = lf   + (size_t)NBH*S_;
    float* e2   = cum  + (size_t)NBH*S_;
    float* pm   = e2   + (size_t)NBH*S_;
    float* gA   = pm   + (size_t)NBH*S_;       // NBH*NT
    float* base = gA   + (size_t)NBH*NT;       // NBH*NT
    float* pM   = base + (size_t)NBH*NT;       // nPart*128
    float* pL   = pM   + (size_t)nPart*128;    // nPart*128
    unsigned short* pOb = (unsigned short*)(pL + (size_t)nPart*128); // nPart*8192
    unsigned short* Qb  = pOb + (size_t)nPart*8192;                  // NE
    unsigned short* Kb  = Qb + NE;                                   // NE
    unsigned short* Vt  = Kb + NE;                                   // NE

    gates_kernel<<<NGATE + NBH*NT, 256, 0, stream>>>(q, k, v, iw, ib, fw, fb,
                                                     ig, lf, Qb, Kb, Vt);
    scan_kernel<<<NBH, 256, 0, stream>>>(lf, ig, cum, e2, pm, gA, base);
    mlstm_part<<<nPart, 256, 0, stream>>>(Qb, Kb, Vt, cum, e2, pm, gA, base, pOb, pM, pL);
    mlstm_combine<<<dim3(NT2, NBH), 256, 0, stream>>>(pOb, pM, pL, w, out);
}

// Round 15
// 127.922 us; speedup vs baseline: 1.0831x; 1.0831x over previous
//
#include <hip/hip_runtime.h>
#include <math.h>

#define DIM 384
#define NH 6
#define DH 64
#define B_ 2
#define S_ 2048
#define EPS 1e-6f
#define LN_EPS 1e-5f
#define G3 (3*DIM)   // 1152
#define LOG2E 1.44269504f
#define KSTR 72      // LDS row stride (ushort): 144 B -> 4-bank rotate/row
#define NT (S_/64)   // 32 q-tiles per (b,h)
#define NSPLIT 4     // t-range splits per q-tile
#define NBH (B_*NH)  // 12
#define NGATE (B_*S_/4)  // 1024 gate blocks

typedef __attribute__((ext_vector_type(8))) short bf16x8;
typedef __attribute__((ext_vector_type(4))) short bf16x4;
typedef __attribute__((ext_vector_type(4))) float f32x4;
typedef __attribute__((ext_vector_type(8))) unsigned short u16x8;

__device__ __forceinline__ unsigned short f2bf(float f){
    unsigned int u = __float_as_uint(f);
    u += 0x7fff + ((u >> 16) & 1);   // round-to-nearest-even
    return (unsigned short)(u >> 16);
}
__device__ __forceinline__ float bf2f(unsigned short u){
    return __uint_as_float(((unsigned int)u) << 16);
}
__device__ __forceinline__ float logsig(float x){
    return fminf(x, 0.f) - log1pf(expf(-fabsf(x)));
}

// ---------------- Kernel 1: gates + Q/K bf16 emission + V-transpose ----------
// Blocks [0,NGATE): gate projections + Qb/Kb emission; blocks [NGATE,..):
// V bf16 transpose (block-uniform branch). (R13 configuration — session best;
// R14's 2-stripe macro tile doubled the serial critical path and regressed.)
__global__ __launch_bounds__(256) void gates_kernel(
    const float* __restrict__ q, const float* __restrict__ k, const float* __restrict__ v,
    const float* __restrict__ iw, const float* __restrict__ ib,
    const float* __restrict__ fw, const float* __restrict__ fb,
    float* __restrict__ ig_out, float* __restrict__ lf_out,
    unsigned short* __restrict__ Qb, unsigned short* __restrict__ Kb,
    unsigned short* __restrict__ Vt) {
    __shared__ unsigned short lt[64*KSTR];
    int tid = threadIdx.x;
    if (blockIdx.x >= NGATE){
        int lin = blockIdx.x - NGATE;     // 0..NBH*NT-1
        int bh = lin / NT;
        int t0 = (lin % NT) * 64;
        int b = bh / NH, h = bh % NH;
        #pragma unroll
        for (int i = 0; i < 4; i++){
            int idx = tid + 256*i;
            int r = idx >> 4;
            int c4 = (idx & 15) * 4;
            float4 x = *(const float4*)(v + ((size_t)b*S_ + t0 + r)*DIM + h*DH + c4);
            lt[(c4+0)*KSTR + r] = f2bf(x.x);
            lt[(c4+1)*KSTR + r] = f2bf(x.y);
            lt[(c4+2)*KSTR + r] = f2bf(x.z);
            lt[(c4+3)*KSTR + r] = f2bf(x.w);
        }
        __syncthreads();
        #pragma unroll
        for (int i = 0; i < 2; i++){
            int idx = tid + 256*i;
            int d = idx >> 3;
            int t8 = (idx & 7) * 8;
            u16x8 o = *(const u16x8*)&lt[d*KSTR + t8];
            *(u16x8*)(Vt + (size_t)bh*DH*S_ + (size_t)d*S_ + t0 + t8) = o;
        }
        return;
    }
    int wave = (blockIdx.x * 256 + tid) >> 6;
    int lane = tid & 63;
    int b = wave / S_, s = wave % S_;
    size_t base = ((size_t)b * S_ + s) * DIM;
    float aI[NH], aF[NH];
    #pragma unroll
    for (int h = 0; h < NH; h++){ aI[h] = 0.f; aF[h] = 0.f; }
    for (int g = lane; g < G3/4; g += 64) {
        int e = g * 4;
        float4 x4;
        if (e < DIM){
            x4 = *(const float4*)(q + base + e);
            ushort4 t; t.x=f2bf(x4.x*0.125f); t.y=f2bf(x4.y*0.125f);
            t.z=f2bf(x4.z*0.125f); t.w=f2bf(x4.w*0.125f);
            *(ushort4*)(Qb + base + e) = t;
        } else if (e < 2*DIM){
            x4 = *(const float4*)(k + base + e - DIM);
            ushort4 t; t.x=f2bf(x4.x); t.y=f2bf(x4.y); t.z=f2bf(x4.z); t.w=f2bf(x4.w);
            *(ushort4*)(Kb + base + e - DIM) = t;
        } else {
            x4 = *(const float4*)(v + base + e - 2*DIM);
        }
        #pragma unroll
        for (int h = 0; h < NH; h++){
            float4 wi = *(const float4*)(iw + h*G3 + e);
            float4 wf = *(const float4*)(fw + h*G3 + e);
            aI[h] = fmaf(x4.x, wi.x, fmaf(x4.y, wi.y, fmaf(x4.z, wi.z, fmaf(x4.w, wi.w, aI[h]))));
            aF[h] = fmaf(x4.x, wf.x, fmaf(x4.y, wf.y, fmaf(x4.z, wf.z, fmaf(x4.w, wf.w, aF[h]))));
        }
    }
    #pragma unroll
    for (int h = 0; h < NH; h++){
        #pragma unroll
        for (int off = 32; off >= 1; off >>= 1){
            aI[h] += __shfl_xor(aI[h], off, 64);
            aF[h] += __shfl_xor(aF[h], off, 64);
        }
    }
    if (lane == 0) {
        #pragma unroll
        for (int h = 0; h < NH; h++){
            ig_out[((size_t)b*NH + h)*S_ + s] = aI[h] + ib[h];
            lf_out[((size_t)b*NH + h)*S_ + s] = logsig(aF[h] + fb[h]);
        }
    }
}

// ---------------- Kernel 2: scan + decay-factor precompute -------------------
__global__ __launch_bounds__(256) void scan_kernel(
    const float* __restrict__ lf, const float* __restrict__ ig,
    float* __restrict__ cum, float* __restrict__ e2, float* __restrict__ pm,
    float* __restrict__ gA, float* __restrict__ baseA){
    int bh = blockIdx.x;
    const float* srcL = lf + (size_t)bh * S_;
    const float* srcI = ig + (size_t)bh * S_;
    float* dstC = cum + (size_t)bh * S_;
    float* dstE = e2 + (size_t)bh * S_;
    float* dstP = pm + (size_t)bh * S_;
    int tid = threadIdx.x;
    float loc[8];
    float run = 0.f;
    #pragma unroll
    for (int j = 0; j < 8; j++){ run += srcL[tid*8 + j]; loc[j] = run; }
    __shared__ float sm[256];
    sm[tid] = run;
    __syncthreads();
    float total = run;
    for (int off = 1; off < 256; off <<= 1){
        float vv = (tid >= off) ? sm[tid - off] : 0.f;
        __syncthreads();
        sm[tid] += vv;
        __syncthreads();
    }
    float excl = sm[tid] - total;
    float c[8];
    #pragma unroll
    for (int j = 0; j < 8; j++){ c[j] = excl + loc[j]; dstC[tid*8 + j] = c[j]; }
    __shared__ float sb[32];
    if ((tid & 7) == 0) sb[tid >> 3] = excl;
    __syncthreads();
    float base_t = sb[tid >> 3];
    float E[8], mloc = -INFINITY;
    #pragma unroll
    for (int j = 0; j < 8; j++){
        E[j] = srcI[tid*8 + j] - c[j] + base_t;
        dstE[tid*8 + j] = exp2f(E[j] * LOG2E);
        mloc = fmaxf(mloc, E[j]);
    }
    __shared__ float smax[256];
    smax[tid] = mloc;
    __syncthreads();
    float carry = -INFINITY;
    int g0 = tid & ~7;
    for (int u = g0; u < tid; u++) carry = fmaxf(carry, smax[u]);
    float runm = carry;
    #pragma unroll
    for (int j = 0; j < 8; j++){
        runm = fmaxf(runm, E[j]);
        dstP[tid*8 + j] = runm;
    }
    if ((tid & 7) == 7) gA[bh*NT + (tid >> 3)] = runm - base_t;
    if ((tid & 7) == 0) baseA[bh*NT + (tid >> 3)] = base_t;
}

// ---------------- Kernel 3a: split-T partial flash-mLSTM (fixed-max) ---------
// R13 configuration: 64-row q-tile, NSPLIT=4 (1536 blocks), fixed-max
// softmax (row max known a priori from scan precompute), LDS double-buffered
// coalesced staging, bf16 partials.
__global__ __launch_bounds__(256) void mlstm_part(
    const unsigned short* __restrict__ Qb, const unsigned short* __restrict__ Kb,
    const unsigned short* __restrict__ Vt,
    const float* __restrict__ cum, const float* __restrict__ e2,
    const float* __restrict__ pm, const float* __restrict__ gA,
    const float* __restrict__ baseA,
    unsigned short* __restrict__ pOb, float* __restrict__ pM, float* __restrict__ pL) {
    int lin = blockIdx.x;            // 0..NBH*NT*NSPLIT-1
    int sp  = lin / NBH;             // split-slot, longest q-tiles first
    int bh  = lin % NBH;
    int st  = (NT - 1) - (sp >> 2);
    int c   = sp & 3;
    int L   = (st + 4) >> 2;         // ceil((st+1)/4)
    int tb0 = c * L;
    int tb1 = min((c + 1) * L, st + 1);
    int pblk = lin;
    int tid = threadIdx.x;

    if (tb0 >= tb1){                 // empty split: neutral partial, exit
        if (tid < 64){ pM[pblk*64 + tid] = -INFINITY; pL[pblk*64 + tid] = 0.f; }
        return;
    }

    __shared__ unsigned short kt[2][64*KSTR];   // K row-major: kt[buf][t][d]
    __shared__ unsigned short vt[2][64*KSTR];   // V transposed: vt[buf][d][t]

    int b = bh / NH, h = bh % NH;
    int s0 = st * 64;
    int wv   = tid >> 6;
    int lane = tid & 63;
    int lq   = lane & 15;
    int quad = lane >> 4;

    const unsigned short* kbT = Kb + (size_t)b*S_*DIM + h*DH;
    const unsigned short* vtB = Vt + (size_t)bh*DH*S_;
    const float* cmb = cum + (size_t)bh*S_;
    const float* e2b = e2 + (size_t)bh*S_;
    const float* gB = gA + bh*NT;
    const float* baseB = baseA + bh*NT;

    int s_glob = s0 + 16*wv + lq;    // s-row this lane's softmax state tracks

    bf16x8 qf[2];
    {
        const unsigned short* qr = Qb + ((size_t)b*S_ + s_glob)*DIM + h*DH;
        qf[0] = *(const bf16x8*)(qr + 8*quad);
        qf[1] = *(const bf16x8*)(qr + 32 + 8*quad);
    }

    float cq   = cmb[s_glob];
    float pm_s = pm[(size_t)bh*S_ + s_glob];   // within-tile prefix max E (diag)

    // ---- prologue: final row max for this split's range ----
    float m = -INFINITY;
    for (int tix = tb0; tix < tb1; tix++)
        if (tix != st) m = fmaxf(m, gB[tix]);
    if (tb1 == st + 1) m = fmaxf(m, pm_s - baseB[st]);
    float mn = cq + m;               // final max of dv over this split's range

    float b_loc = 0.f;               // per-lane partial sum (16 t's per lane)
    f32x4 oacc[4];                   // O C-layout: row s=4quad+r, col d=16cg+lq
    #pragma unroll
    for (int cg = 0; cg < 4; cg++) oacc[cg] = (f32x4){0.f,0.f,0.f,0.f};

    int sr[2], sc[2];
    #pragma unroll
    for (int i = 0; i < 2; i++){
        int idx = tid + 256*i;
        sr[i] = idx >> 3;
        sc[i] = (idx & 7) * 8;
    }

    // preload + stage tile tb0 into buffer 0
    u16x8 kreg[2], vreg[2];
    {
        const unsigned short* kb = kbT + (size_t)(tb0*64)*DIM;
        const unsigned short* vb = vtB + tb0*64;
        #pragma unroll
        for (int i = 0; i < 2; i++){
            kreg[i] = *(const u16x8*)(kb + (size_t)sr[i]*DIM + sc[i]);
            vreg[i] = *(const u16x8*)(vb + (size_t)sr[i]*S_ + sc[i]);
        }
        #pragma unroll
        for (int i = 0; i < 2; i++){
            *(u16x8*)&kt[0][sr[i]*KSTR + sc[i]] = kreg[i];
            *(u16x8*)&vt[0][sr[i]*KSTR + sc[i]] = vreg[i];
        }
    }
    __syncthreads();

    int bufi = 0;
    for (int t0 = tb0*64; t0 < tb1*64; t0 += 64){
        bool more = (t0 + 64 < tb1*64);
        if (more){
            const unsigned short* kb = kbT + (size_t)(t0 + 64)*DIM;
            const unsigned short* vb = vtB + (t0 + 64);
            #pragma unroll
            for (int i = 0; i < 2; i++){
                kreg[i] = *(const u16x8*)(kb + (size_t)sr[i]*DIM + sc[i]);
                vreg[i] = *(const u16x8*)(vb + (size_t)sr[i]*S_ + sc[i]);
            }
        }

        int tix = t0 >> 6;
        float base_t = baseB[tix];
        // ws = exp(dv - mn)/e2 = exp(-(m + base_t))
        float ws = exp2f(-(m + base_t) * LOG2E);
        float4 e2v[4];
        #pragma unroll
        for (int tb = 0; tb < 4; tb++)
            e2v[tb] = *(const float4*)(e2b + t0 + 16*tb + 4*quad);

        // ---- matmul1: S^T blocks (read from current buffer) ----
        const unsigned short* ktc = kt[bufi];
        const unsigned short* vtc = vt[bufi];
        f32x4 st4[4];
        #pragma unroll
        for (int tb = 0; tb < 4; tb++) st4[tb] = (f32x4){0.f,0.f,0.f,0.f};
        #pragma unroll
        for (int ks = 0; ks < 2; ks++){
            #pragma unroll
            for (int tb = 0; tb < 4; tb++){
                bf16x8 af = *(const bf16x8*)&ktc[(16*tb + lq)*KSTR + 32*ks + 8*quad];
                st4[tb] = __builtin_amdgcn_mfma_f32_16x16x32_bf16(af, qf[ks], st4[tb], 0, 0, 0);
            }
        }

        // ---- fixed-max softmax: pv = st4 * ws * e2[t], with diag mask ----
        bool diag = (t0 == s0);
        float pv[4][4];
        #pragma unroll
        for (int tb = 0; tb < 4; tb++)
            #pragma unroll
            for (int r = 0; r < 4; r++)
                pv[tb][r] = st4[tb][r] * (ws * e2v[tb][r]);
        if (diag){
            #pragma unroll
            for (int tb = 0; tb < 4; tb++)
                #pragma unroll
                for (int r = 0; r < 4; r++)
                    if (t0 + 16*tb + 4*quad + r > s_glob) pv[tb][r] = 0.f;
        }
        bf16x4 pf[4];   // P^T in 16x16x16 A-operand layout
        #pragma unroll
        for (int tb = 0; tb < 4; tb++){
            #pragma unroll
            for (int r = 0; r < 4; r++){
                b_loc += pv[tb][r];
                pf[tb][r] = (short)f2bf(pv[tb][r]);
            }
        }

        // ---- matmul2: O += P @ V (no rescale needed) ----
        #pragma unroll
        for (int tb = 0; tb < 4; tb++){
            #pragma unroll
            for (int cg = 0; cg < 4; cg++){
                bf16x4 vf = *(const bf16x4*)&vtc[(16*cg + lq)*KSTR + 16*tb + 4*quad];
                oacc[cg] = __builtin_amdgcn_mfma_f32_16x16x16bf16_1k(pf[tb], vf, oacc[cg], 0, 0, 0);
            }
        }

        // ---- stage prefetched tile into the OTHER buffer, one barrier ----
        if (more){
            #pragma unroll
            for (int i = 0; i < 2; i++){
                *(u16x8*)&kt[bufi^1][sr[i]*KSTR + sc[i]] = kreg[i];
                *(u16x8*)&vt[bufi^1][sr[i]*KSTR + sc[i]] = vreg[i];
            }
            __syncthreads();
            bufi ^= 1;
        }
    }

    // ---- deferred row-sum reduction + write partials (bf16) ----
    b_loc += __shfl_xor(b_loc, 16, 64);
    b_loc += __shfl_xor(b_loc, 32, 64);
    unsigned short* po = pOb + (size_t)pblk * 4096;
    #pragma unroll
    for (int r = 0; r < 4; r++){
        int row = 16*wv + 4*quad + r;
        #pragma unroll
        for (int cg = 0; cg < 4; cg++)
            po[row*64 + 16*cg + lq] = f2bf(oacc[cg][r]);
    }
    if (quad == 0){
        pM[pblk*64 + 16*wv + lq] = mn;
        pL[pblk*64 + 16*wv + lq] = b_loc;
    }
}

// ---------------- Kernel 3b: combine partials + normalizer + LayerNorm -------
__global__ __launch_bounds__(256) void mlstm_combine(
    const unsigned short* __restrict__ pOb, const float* __restrict__ pM,
    const float* __restrict__ pL, const float* __restrict__ w,
    float* __restrict__ out) {
    int st = blockIdx.x;
    int bh = blockIdx.y;
    int b = bh / NH, h = bh % NH;
    int tid = threadIdx.x;
    int cl = (tid & 15) * 4;       // col base (x4)
    int rb = tid >> 4;             // row within 16-row band

    int pblk[NSPLIT];
    #pragma unroll
    for (int p = 0; p < NSPLIT; p++)
        pblk[p] = (((NT - 1 - st) << 2) + p) * NBH + bh;

    float4 wv4 = *(const float4*)(w + h*DH + cl);

    #pragma unroll
    for (int pass = 0; pass < 4; pass++){
        int row = pass*16 + rb;
        float mp[NSPLIT], lp[NSPLIT];
        float mmax = -INFINITY;
        #pragma unroll
        for (int p = 0; p < NSPLIT; p++){
            mp[p] = pM[pblk[p]*64 + row];
            lp[p] = pL[pblk[p]*64 + row];
            mmax = fmaxf(mmax, mp[p]);
        }
        float l = 0.f;
        float ox = 0.f, oy = 0.f, oz = 0.f, ow = 0.f;
        #pragma unroll
        for (int p = 0; p < NSPLIT; p++){
            if (mp[p] != -INFINITY){           // skip empty splits
                float wp = exp2f((mp[p] - mmax) * LOG2E);
                l += wp * lp[p];
                ushort4 t4 = *(const ushort4*)(pOb + (size_t)pblk[p]*4096 + row*64 + cl);
                ox += wp*bf2f(t4.x); oy += wp*bf2f(t4.y);
                oz += wp*bf2f(t4.z); ow += wp*bf2f(t4.w);
            }
        }
        float nrm = fmaxf(fabsf(l), exp2f(-mmax * LOG2E));
        float inv = 1.f / (nrm + EPS);
        float x[4] = {ox*inv, oy*inv, oz*inv, ow*inv};
        float s1 = x[0]+x[1]+x[2]+x[3];
        float s2 = x[0]*x[0]+x[1]*x[1]+x[2]*x[2]+x[3]*x[3];
        #pragma unroll
        for (int off = 8; off >= 1; off >>= 1){
            s1 += __shfl_xor(s1, off, 64);
            s2 += __shfl_xor(s2, off, 64);
        }
        float mean = s1 * (1.f/64.f);
        float var  = s2 * (1.f/64.f) - mean*mean;
        float rstd = rsqrtf(var + LN_EPS);
        float4 oo;
        oo.x = (x[0]-mean)*rstd*(1.f + wv4.x);
        oo.y = (x[1]-mean)*rstd*(1.f + wv4.y);
        oo.z = (x[2]-mean)*rstd*(1.f + wv4.z);
        oo.w = (x[3]-mean)*rstd*(1.f + wv4.w);
        *(float4*)(out + ((size_t)b*S_ + st*64 + row)*DIM + h*DH + cl) = oo;
    }
}

extern "C" void kernel_launch(void* const* d_in, const int* in_sizes, int n_in,
                              void* d_out, int out_size, void* d_ws, size_t ws_size,
                              hipStream_t stream) {
    const float* q  = (const float*)d_in[0];
    const float* k  = (const float*)d_in[1];
    const float* v  = (const float*)d_in[2];
    const float* iw = (const float*)d_in[3];
    const float* ib = (const float*)d_in[4];
    const float* fw = (const float*)d_in[5];
    const float* fb = (const float*)d_in[6];
    const float* w  = (const float*)d_in[7];
    float* out = (float*)d_out;

    const int nPart = NBH * NT * NSPLIT;       // 1536
    const size_t NE = (size_t)B_ * S_ * DIM;   // 1.57M elems
    float* ig   = (float*)d_ws;                // NBH*S
    float* lf   = ig   + (size_t)NBH*S_;
    float* cum  = lf   + (size_t)NBH*S_;
    float* e2   = cum  + (size_t)NBH*S_;
    float* pm   = e2   + (size_t)NBH*S_;
    float* gA   = pm   + (size_t)NBH*S_;       // NBH*NT
    float* base = gA   + (size_t)NBH*NT;       // NBH*NT
    float* pM   = base + (size_t)NBH*NT;       // nPart*64
    float* pL   = pM   + (size_t)nPart*64;     // nPart*64
    unsigned short* pOb = (unsigned short*)(pL + (size_t)nPart*64);  // nPart*4096
    unsigned short* Qb  = pOb + (size_t)nPart*4096;                  // NE
    unsigned short* Kb  = Qb + NE;                                   // NE
    unsigned short* Vt  = Kb + NE;                                   // NE

    gates_kernel<<<NGATE + NBH*NT, 256, 0, stream>>>(q, k, v, iw, ib, fw, fb,
                                                     ig, lf, Qb, Kb, Vt);
    scan_kernel<<<NBH, 256, 0, stream>>>(lf, ig, cum, e2, pm, gA, base);
    mlstm_part<<<nPart, 256, 0, stream>>>(Qb, Kb, Vt, cum, e2, pm, gA, base, pOb, pM, pL);
    mlstm_combine<<<dim3(NT, NBH), 256, 0, stream>>>(pOb, pM, pL, w, out);
}